// Round 3
// baseline (395.355 us; speedup 1.0000x reference)
//
#include <hip/hip_runtime.h>

// Multi-head VQ: inputs (16,2048,1024) f32, embeddings (4,64,256) f32.
// Out flat f32: quantized_st[33554432] | loss[1] | indices[131072 as float].
// Decomposition: lane = token (64 tokens/wave), wave owns one head slice.
// e is wave-uniform -> scalar loads feeding v_fmac's SGPR operand.
// quantized_st written as q directly (|x+(q-x) - q| ~ 1e-6 << 1.26 thr).
// loss accumulated as the min distance (== ||q-x||^2 within ~1e-6 rel).

#define HH   4
#define KK   64
#define HD   256
#define DD   1024
#define NTOK 32768
#define NDQ  33554432ull
#define NWAVES 2048   // (32768/64) * 4 heads

__global__ void vq_cbq(const float* __restrict__ emb, float* __restrict__ cbq)
{
    // 256 threads: one per (h,k). Rounded products, sequential sum.
    const int t = threadIdx.x;
    const float* e = emb + (size_t)t * HD;
    float s = 0.f;
    {
        #pragma clang fp contract(off)
        for (int d = 0; d < HD; ++d) {
            float p = e[d] * e[d];
            s = s + p;
        }
    }
    cbq[t] = s;
}

__global__ __launch_bounds__(256, 2) void vq_main(
    const float* __restrict__ x, const float* __restrict__ emb,
    const float* __restrict__ cbq, float* __restrict__ out,
    double* __restrict__ partial)
{
    const int h    = blockIdx.y;
    const int wave = threadIdx.x >> 6;
    const int lane = threadIdx.x & 63;
    const int tok0 = blockIdx.x * 256 + wave * 64;  // wave's 64 tokens
    const int tok  = tok0 + lane;                   // this lane's token

    const float* __restrict__ eh   = emb + (size_t)h * (KK * HD);
    const float* __restrict__ xrow = x + (size_t)tok * DD + (size_t)h * HD;
    const float* __restrict__ cbh  = cbq + h * KK;

    float acc[KK];
    #pragma unroll
    for (int k = 0; k < KK; ++k) acc[k] = 0.f;

    // numpy-pairwise input_sq replica: 256 = 128+128, each via 8 strided
    // accumulators r0..r7 (i outer, j inner), rounded (non-fused) products.
    float r0=0.f,r1=0.f,r2=0.f,r3=0.f,r4=0.f,r5=0.f,r6=0.f,r7=0.f;
    float halfA = 0.f;

    // Manual double-buffer of this lane's 16-dim chunk (4x float4).
    float4 n0 = *(const float4*)(xrow + 0);
    float4 n1 = *(const float4*)(xrow + 4);
    float4 n2 = *(const float4*)(xrow + 8);
    float4 n3 = *(const float4*)(xrow + 12);

    for (int c = 0; c < 16; ++c) {
        const float4 a0 = n0, a1 = n1, a2 = n2, a3 = n3;
        if (c < 15) {
            const float* p = xrow + (c + 1) * 16;
            n0 = *(const float4*)(p + 0);
            n1 = *(const float4*)(p + 4);
            n2 = *(const float4*)(p + 8);
            n3 = *(const float4*)(p + 12);
        }
        const float xv[16] = { a0.x,a0.y,a0.z,a0.w, a1.x,a1.y,a1.z,a1.w,
                               a2.x,a2.y,a2.z,a2.w, a3.x,a3.y,a3.z,a3.w };
        const float* __restrict__ ec = eh + c * 16;   // wave-uniform
        #pragma unroll
        for (int k = 0; k < KK; ++k) {
            const float* __restrict__ ek = ec + k * HD;  // uniform -> s_load
            float a = acc[k];
            #pragma unroll
            for (int j = 0; j < 16; ++j)
                a = __builtin_fmaf(ek[j], xv[j], a);
            acc[k] = a;
        }
        {   // input_sq partials: i = 2c and 2c+1 in numpy's 8-stride pattern
            #pragma clang fp contract(off)
            r0 = r0 + xv[0]*xv[0];  r1 = r1 + xv[1]*xv[1];
            r2 = r2 + xv[2]*xv[2];  r3 = r3 + xv[3]*xv[3];
            r4 = r4 + xv[4]*xv[4];  r5 = r5 + xv[5]*xv[5];
            r6 = r6 + xv[6]*xv[6];  r7 = r7 + xv[7]*xv[7];
            r0 = r0 + xv[8]*xv[8];  r1 = r1 + xv[9]*xv[9];
            r2 = r2 + xv[10]*xv[10]; r3 = r3 + xv[11]*xv[11];
            r4 = r4 + xv[12]*xv[12]; r5 = r5 + xv[13]*xv[13];
            r6 = r6 + xv[14]*xv[14]; r7 = r7 + xv[15]*xv[15];
        }
        if (c == 7) {   // close first 128-block, numpy combine order
            halfA = ((r0 + r1) + (r2 + r3)) + ((r4 + r5) + (r6 + r7));
            r0=r1=r2=r3=r4=r5=r6=r7=0.f;
        }
    }
    const float halfB = ((r0 + r1) + (r2 + r3)) + ((r4 + r5) + (r6 + r7));
    const float isq = halfA + halfB;

    // In-lane argmin, ref rounding order: (isq + cbq[k]) - 2*dot[k].
    // Strict < keeps the first index on ties (matches np.argmin).
    float bv = (isq + cbh[0]) - 2.0f * acc[0];
    int   bi = 0;
    #pragma unroll
    for (int k = 1; k < KK; ++k) {
        float d = (isq + cbh[k]) - 2.0f * acc[k];
        bool lt = d < bv;
        bv = lt ? d : bv;
        bi = lt ? k : bi;
    }

    out[NDQ + 1 + (size_t)tok * HH + h] = (float)bi;

    // Loss partial: min distance == ||q - x||^2 (within ~1e-6 relative).
    float loss = bv;
    #pragma unroll
    for (int m = 1; m < 64; m <<= 1) loss += __shfl_xor(loss, m);
    if (lane == 0) {
        const int wgid = (blockIdx.y * gridDim.x + blockIdx.x) * 4 + wave;
        partial[wgid] = (double)loss;
    }

    // Epilogue: write q rows directly (coalesced; codebook is L2-resident).
    for (int t = 0; t < 64; ++t) {
        const int kst = __shfl(bi, t);
        const float4 q4 = *(const float4*)(eh + (size_t)kst * HD + lane * 4);
        *(float4*)(out + (size_t)(tok0 + t) * DD + (size_t)h * HD + lane * 4) = q4;
    }
}

__global__ void vq_finalize(const double* __restrict__ partial,
                            float* __restrict__ out)
{
    const int lane = threadIdx.x & 63;
    double s = 0.0;
    for (int i = 0; i < NWAVES / 64; ++i) s += partial[i * 64 + lane];
    #pragma unroll
    for (int m = 1; m < 64; m <<= 1) s += __shfl_xor(s, m);
    if (lane == 0) {
        const float mv = (float)(s / (double)NDQ);
        out[NDQ] = mv + 0.5f * mv;   // q_latent + 0.5*e_latent (equal values)
    }
}

extern "C" void kernel_launch(void* const* d_in, const int* in_sizes, int n_in,
                              void* d_out, int out_size, void* d_ws, size_t ws_size,
                              hipStream_t stream)
{
    const float* x   = (const float*)d_in[0];
    const float* emb = (const float*)d_in[1];
    float* out = (float*)d_out;
    double* partial = (double*)d_ws;                       // 2048 doubles
    float*  cbq     = (float*)((char*)d_ws + NWAVES * 8);  // 256 floats

    vq_cbq<<<1, dim3(256), 0, stream>>>(emb, cbq);
    vq_main<<<dim3(NTOK / 256, HH), dim3(256), 0, stream>>>(x, emb, cbq, out, partial);
    vq_finalize<<<1, dim3(64), 0, stream>>>(partial, out);
}